// Round 4
// baseline (15291.734 us; speedup 1.0000x reference)
//
#include <hip/hip_runtime.h>
#include <hip/hip_bf16.h>
#include <math.h>

#define Bn  16
#define Sn  626
#define Dn  768
#define Hn  12
#define HDn 64
#define Mn  (Bn*Sn)        // 10016
#define BHn (Bn*Hn)        // 192

#define QT   16
#define KTc  32
#define SPAD 628

// workspace float offsets
#define WS_TENSOR ((size_t)Bn*Sn*Dn)        // 7,692,288 floats each
#define Q_OFF   ((size_t)0)
#define K_OFF   (WS_TENSOR)
#define V_OFF   (2*WS_TENSOR)
#define CTX_OFF (3*WS_TENSOR)
#define COL_OFF (4*WS_TENSOR)

// output element offsets (fp32 elements), concatenated in return order:
// attention_output (16,626,768) | attention_probs (16,12,626,626) | contribution (16,12,626)
#define OUT1_OFF ((size_t)Bn*Sn*Dn)                      // attention_probs
#define OUT2_OFF (OUT1_OFF + (size_t)BHn*Sn*Sn)          // contribution

// ---------------------------------------------------------------------------
// Kernel 1: fused QKV projection.  C = hidden(M x 768) @ W(768 x 768) + b,
// fp32 in, fp32 accumulate, stored to ws in (b, h, s, hd) fp32 layout.
// ---------------------------------------------------------------------------
__global__ __launch_bounds__(256) void qkv_gemm(
    const float* __restrict__ A,
    const float* __restrict__ Wq, const float* __restrict__ bq,
    const float* __restrict__ Wk, const float* __restrict__ bk,
    const float* __restrict__ Wv, const float* __restrict__ bv,
    float* __restrict__ ws)
{
    __shared__ float As[8][128];   // transposed: As[k][m]
    __shared__ float Bs[8][128];

    const int z = blockIdx.z;
    const float* __restrict__ W    = (z == 0) ? Wq : (z == 1) ? Wk : Wv;
    const float* __restrict__ bias = (z == 0) ? bq : (z == 1) ? bk : bv;
    float* __restrict__ out = ws + (size_t)z * WS_TENSOR;

    const int m0 = blockIdx.x * 128;
    const int n0 = blockIdx.y * 128;
    const int t  = threadIdx.x;
    const int tx = t & 15;
    const int ty = t >> 4;

    float acc[8][8];
#pragma unroll
    for (int i = 0; i < 8; ++i)
#pragma unroll
        for (int j = 0; j < 8; ++j) acc[i][j] = 0.f;

    const int a_m = t >> 1;
    const int a_k = (t & 1) * 4;
    const int b_k = t >> 5;
    const int b_n = (t & 31) * 4;
    const int arow = m0 + a_m;

    for (int k0 = 0; k0 < Dn; k0 += 8) {
        float4 av = make_float4(0.f, 0.f, 0.f, 0.f);
        if (arow < Mn) av = *(const float4*)(A + (size_t)arow*Dn + k0 + a_k);
        As[a_k+0][a_m] = av.x;
        As[a_k+1][a_m] = av.y;
        As[a_k+2][a_m] = av.z;
        As[a_k+3][a_m] = av.w;
        *(float4*)&Bs[b_k][b_n] =
            *(const float4*)(W + (size_t)(k0 + b_k)*Dn + n0 + b_n);
        __syncthreads();
#pragma unroll
        for (int kk = 0; kk < 8; ++kk) {
            float a[8], b[8];
            *(float4*)&a[0] = *(const float4*)&As[kk][ty*4];
            *(float4*)&a[4] = *(const float4*)&As[kk][64 + ty*4];
            *(float4*)&b[0] = *(const float4*)&Bs[kk][tx*4];
            *(float4*)&b[4] = *(const float4*)&Bs[kk][64 + tx*4];
#pragma unroll
            for (int i = 0; i < 8; ++i)
#pragma unroll
                for (int j = 0; j < 8; ++j)
                    acc[i][j] += a[i]*b[j];
        }
        __syncthreads();
    }

#pragma unroll
    for (int i = 0; i < 8; ++i) {
        int ml = (i < 4) ? (ty*4 + i) : (64 + ty*4 + i - 4);
        int m = m0 + ml;
        if (m >= Mn) continue;
        int bb = m / Sn;
        int s  = m - bb*Sn;
#pragma unroll
        for (int jg = 0; jg < 2; ++jg) {
            int nl = (jg == 0) ? (tx*4) : (64 + tx*4);
            int n  = n0 + nl;
            int h  = n >> 6;
            int hd = n & 63;
            float4 r;
            r.x = acc[i][jg*4+0] + bias[n+0];
            r.y = acc[i][jg*4+1] + bias[n+1];
            r.z = acc[i][jg*4+2] + bias[n+2];
            r.w = acc[i][jg*4+3] + bias[n+3];
            *(float4*)(out + (((size_t)(bb*Hn + h)*Sn + s)*HDn + hd)) = r;
        }
    }
}

// ---------------------------------------------------------------------------
// Kernel 2: attention core.  One block = one (b,h) x 16 query rows.
// scores -> row0 fix -> col0 extract -> row softmax (probs fp32 to d_out)
// -> P @ V -> ctx workspace.
// ---------------------------------------------------------------------------
__global__ __launch_bounds__(256) void attn_kernel(
    const float* __restrict__ qws, const float* __restrict__ kws,
    const float* __restrict__ vws, const int* __restrict__ mask,
    float* __restrict__ probs_out,
    float* __restrict__ ctxws, float* __restrict__ colws)
{
    __shared__ float sc[QT][SPAD];
    __shared__ float qs[QT][68];
    __shared__ float ks[KTc][68];   // reused for V in phase 4
    __shared__ float red[256];
    __shared__ float rA[QT];

    const int bh = blockIdx.y;
    const int bb = bh / Hn;
    const int q0 = blockIdx.x * QT;
    const int t  = threadIdx.x;

    // stage Q tile (zero-padded rows beyond S)
    {
        int r = t >> 4;
        int d = (t & 15) * 4;
        int q = q0 + r;
        float4 v = make_float4(0.f, 0.f, 0.f, 0.f);
        if (q < Sn) v = *(const float4*)(qws + ((size_t)bh*Sn + q)*HDn + d);
        *(float4*)&qs[r][d] = v;
    }
    __syncthreads();

    // phase 1: scores = Q K^T / 8
    const int key = t & 31;
    const int qg  = t >> 5;           // 0..7 -> rows qg*2, qg*2+1
    for (int kc = 0; kc < Sn; kc += KTc) {
        int csz = min(KTc, Sn - kc);
        {
            int ki = t >> 3;
            int d  = (t & 7) * 8;
            if (ki < csz) {
                const float* src = kws + ((size_t)bh*Sn + kc + ki)*HDn + d;
                *(float4*)&ks[ki][d]   = *(const float4*)(src);
                *(float4*)&ks[ki][d+4] = *(const float4*)(src + 4);
            }
        }
        __syncthreads();
        if (key < csz) {
            const float4* kr = (const float4*)&ks[key][0];
            const float4* qa = (const float4*)&qs[qg*2][0];
            const float4* qb = (const float4*)&qs[qg*2+1][0];
            float s0 = 0.f, s1 = 0.f;
#pragma unroll
            for (int d4 = 0; d4 < 16; ++d4) {
                float4 kv  = kr[d4];
                float4 q0v = qa[d4];
                float4 q1v = qb[d4];
                s0 += q0v.x*kv.x + q0v.y*kv.y + q0v.z*kv.z + q0v.w*kv.w;
                s1 += q1v.x*kv.x + q1v.y*kv.y + q1v.z*kv.z + q1v.w*kv.w;
            }
            sc[qg*2  ][kc + key] = s0 * 0.125f;
            sc[qg*2+1][kc + key] = s1 * 0.125f;
        }
        __syncthreads();
    }

    // phase 2: row-0 adjustment (global q==0 lives in q-tile 0, row 0).
    // max_as computed BEFORE modification; add max*0.25 where mask626==0.
    if (blockIdx.x == 0) {
        float lm = -INFINITY;
        for (int k = t; k < Sn; k += 256) lm = fmaxf(lm, sc[0][k]);
        red[t] = lm;
        __syncthreads();
        for (int off = 128; off > 0; off >>= 1) {
            if (t < off) red[t] = fmaxf(red[t], red[t + off]);
            __syncthreads();
        }
        float addv = red[0] * 0.25f;   // COEFF_MAX
        for (int k = t; k < Sn; k += 256) {
            int mz = (k == 0) ? 0 : mask[(size_t)bb*(Sn-1) + k - 1];
            if (mz == 0) sc[0][k] += addv;
        }
        __syncthreads();
    }

    // col-0 extraction (post row-0 fix, pre softmax) for contribution
    if (t < QT) {
        int q = q0 + t;
        if (q < Sn) colws[(size_t)bh*Sn + q] = sc[t][0];
    }

    // phase 3: row softmax; write probs (fp32) and keep fp32 probs in LDS
    const int r = t >> 4;
    const int j = t & 15;
    {
        float lm = -INFINITY;
        for (int k = j; k < Sn; k += 16) lm = fmaxf(lm, sc[r][k]);
        red[t] = lm;
        __syncthreads();
        if (j == 0) {
            float m = red[r*16];
#pragma unroll
            for (int i = 1; i < 16; ++i) m = fmaxf(m, red[r*16 + i]);
            rA[r] = m;
        }
        __syncthreads();
        float rm = rA[r];
        float ls = 0.f;
        for (int k = j; k < Sn; k += 16) {
            float e = expf(sc[r][k] - rm);
            sc[r][k] = e;
            ls += e;
        }
        red[t] = ls;
        __syncthreads();
        if (j == 0) {
            float ssum = 0.f;
#pragma unroll
            for (int i = 0; i < 16; ++i) ssum += red[r*16 + i];
            rA[r] = ssum;
        }
        __syncthreads();
        float inv = 1.0f / rA[r];
        int q = q0 + r;
        float* orow = probs_out + ((size_t)bh*Sn + q)*Sn;
        for (int k = j; k < Sn; k += 16) {
            float p = sc[r][k] * inv;
            sc[r][k] = p;
            if (q < Sn) orow[k] = p;
        }
        __syncthreads();
    }

    // phase 4: ctx = P @ V  (thread: row r, cols j*4..j*4+3)
    float4 accv = make_float4(0.f, 0.f, 0.f, 0.f);
    for (int kc = 0; kc < Sn; kc += KTc) {
        int csz = min(KTc, Sn - kc);
        {
            int ki = t >> 3;
            int d  = (t & 7) * 8;
            if (ki < csz) {
                const float* src = vws + ((size_t)bh*Sn + kc + ki)*HDn + d;
                *(float4*)&ks[ki][d]   = *(const float4*)(src);
                *(float4*)&ks[ki][d+4] = *(const float4*)(src + 4);
            }
        }
        __syncthreads();
        for (int kk = 0; kk < csz; ++kk) {
            float p = sc[r][kc + kk];
            float4 vv = *(const float4*)&ks[kk][j*4];
            accv.x += p*vv.x; accv.y += p*vv.y;
            accv.z += p*vv.z; accv.w += p*vv.w;
        }
        __syncthreads();
    }
    {
        int q = q0 + r;
        if (q < Sn)
            *(float4*)(ctxws + ((size_t)bh*Sn + q)*HDn + j*4) = accv;
    }
}

// ---------------------------------------------------------------------------
// Kernel 3: contribution = softmax over q of scores[:,:,q,0]
// ---------------------------------------------------------------------------
__global__ __launch_bounds__(256) void contrib_kernel(
    const float* __restrict__ colws, float* __restrict__ out2)
{
    __shared__ float red[256];
    const int bh = blockIdx.x;
    const int t  = threadIdx.x;
    const float* col = colws + (size_t)bh*Sn;

    float lm = -INFINITY;
    for (int q = t; q < Sn; q += 256) lm = fmaxf(lm, col[q]);
    red[t] = lm;
    __syncthreads();
    for (int off = 128; off > 0; off >>= 1) {
        if (t < off) red[t] = fmaxf(red[t], red[t + off]);
        __syncthreads();
    }
    float mx = red[0];
    __syncthreads();
    float ls = 0.f;
    for (int q = t; q < Sn; q += 256) ls += expf(col[q] - mx);
    red[t] = ls;
    __syncthreads();
    for (int off = 128; off > 0; off >>= 1) {
        if (t < off) red[t] += red[t + off];
        __syncthreads();
    }
    float inv = 1.0f / red[0];
    for (int q = t; q < Sn; q += 256)
        out2[(size_t)bh*Sn + q] = expf(col[q] - mx) * inv;
}

// ---------------------------------------------------------------------------
// Kernel 4: attention_output = ctx @ Wo + bo  (fp32 in, fp32 out)
// ---------------------------------------------------------------------------
__global__ __launch_bounds__(256) void out_gemm(
    const float* __restrict__ ctx,
    const float* __restrict__ Wo, const float* __restrict__ bo,
    float* __restrict__ out0)
{
    __shared__ float As[8][128];
    __shared__ float Bs[8][128];

    const int m0 = blockIdx.x * 128;
    const int n0 = blockIdx.y * 128;
    const int t  = threadIdx.x;
    const int tx = t & 15;
    const int ty = t >> 4;

    float acc[8][8];
#pragma unroll
    for (int i = 0; i < 8; ++i)
#pragma unroll
        for (int j = 0; j < 8; ++j) acc[i][j] = 0.f;

    const int a_m = t >> 1;
    const int a_k = (t & 1) * 4;
    const int b_k = t >> 5;
    const int b_n = (t & 31) * 4;
    const int arow = m0 + a_m;
    int bb = 0, s = 0;
    if (arow < Mn) { bb = arow / Sn; s = arow - bb*Sn; }

    for (int k0 = 0; k0 < Dn; k0 += 8) {
        float4 av = make_float4(0.f, 0.f, 0.f, 0.f);
        if (arow < Mn) {
            int k = k0 + a_k;
            av = *(const float4*)(ctx +
                 (((size_t)(bb*Hn + (k >> 6))*Sn + s)*HDn + (k & 63)));
        }
        As[a_k+0][a_m] = av.x;
        As[a_k+1][a_m] = av.y;
        As[a_k+2][a_m] = av.z;
        As[a_k+3][a_m] = av.w;
        *(float4*)&Bs[b_k][b_n] =
            *(const float4*)(Wo + (size_t)(k0 + b_k)*Dn + n0 + b_n);
        __syncthreads();
#pragma unroll
        for (int kk = 0; kk < 8; ++kk) {
            float a[8], b[8];
            *(float4*)&a[0] = *(const float4*)&As[kk][ty*4];
            *(float4*)&a[4] = *(const float4*)&As[kk][64 + ty*4];
            *(float4*)&b[0] = *(const float4*)&Bs[kk][tx*4];
            *(float4*)&b[4] = *(const float4*)&Bs[kk][64 + tx*4];
#pragma unroll
            for (int i = 0; i < 8; ++i)
#pragma unroll
                for (int j = 0; j < 8; ++j)
                    acc[i][j] += a[i]*b[j];
        }
        __syncthreads();
    }

#pragma unroll
    for (int i = 0; i < 8; ++i) {
        int ml = (i < 4) ? (ty*4 + i) : (64 + ty*4 + i - 4);
        int m = m0 + ml;
        if (m >= Mn) continue;
#pragma unroll
        for (int jg = 0; jg < 2; ++jg) {
            int nl = (jg == 0) ? (tx*4) : (64 + tx*4);
            int n  = n0 + nl;
            float4 r;
            r.x = acc[i][jg*4+0] + bo[n+0];
            r.y = acc[i][jg*4+1] + bo[n+1];
            r.z = acc[i][jg*4+2] + bo[n+2];
            r.w = acc[i][jg*4+3] + bo[n+3];
            *(float4*)(out0 + (size_t)m*Dn + n) = r;
        }
    }
}

// ---------------------------------------------------------------------------
extern "C" void kernel_launch(void* const* d_in, const int* in_sizes, int n_in,
                              void* d_out, int out_size, void* d_ws, size_t ws_size,
                              hipStream_t stream)
{
    (void)in_sizes; (void)n_in; (void)out_size; (void)ws_size;
    const float* hidden = (const float*)d_in[0];
    const int*   mask   = (const int*)d_in[1];
    const float* Wq = (const float*)d_in[2];
    const float* bq = (const float*)d_in[3];
    const float* Wk = (const float*)d_in[4];
    const float* bk = (const float*)d_in[5];
    const float* Wv = (const float*)d_in[6];
    const float* bv = (const float*)d_in[7];
    const float* Wo = (const float*)d_in[8];
    const float* bo = (const float*)d_in[9];

    float* ws  = (float*)d_ws;
    float* out = (float*)d_out;

    float* qws   = ws + Q_OFF;
    float* kws   = ws + K_OFF;
    float* vws   = ws + V_OFF;
    float* ctxws = ws + CTX_OFF;
    float* colws = ws + COL_OFF;

    qkv_gemm<<<dim3((Mn + 127)/128, Dn/128, 3), 256, 0, stream>>>(
        hidden, Wq, bq, Wk, bk, Wv, bv, ws);

    attn_kernel<<<dim3((Sn + QT - 1)/QT, BHn), 256, 0, stream>>>(
        qws, kws, vws, mask, out + OUT1_OFF, ctxws, colws);

    contrib_kernel<<<BHn, 256, 0, stream>>>(colws, out + OUT2_OFF);

    out_gemm<<<dim3((Mn + 127)/128, Dn/128), 256, 0, stream>>>(
        ctxws, Wo, bo, out);
}